// Round 6
// baseline (464.485 us; speedup 1.0000x reference)
//
#include <hip/hip_runtime.h>
#include <hip/hip_fp16.h>

#define D 128
#define NB_MAX 1024
#define CNT_BLOCKS 512

using f32x4  = __attribute__((ext_vector_type(4))) float;
using half8  = __attribute__((ext_vector_type(8))) _Float16;
using short8 = __attribute__((ext_vector_type(8))) short;

#define AS1(p) ((const __attribute__((address_space(1))) void*)(p))
#define AS3(p) ((__attribute__((address_space(3))) void*)(p))

// v_fma_mix_f32: acc += (float)(f16 half of dw) * 1.0f  — one VALU op replaces cvt+fma
#define FMA_MIX_LO(acc, dw, one) \
    asm("v_fma_mix_f32 %0, %1, %2, %0 op_sel:[0,0,0] op_sel_hi:[1,0,0]" \
        : "+v"(acc) : "v"(dw), "v"(one))
#define FMA_MIX_HI(acc, dw, one) \
    asm("v_fma_mix_f32 %0, %1, %2, %0 op_sel:[1,0,0] op_sel_hi:[1,0,0]" \
        : "+v"(acc) : "v"(dw), "v"(one))

// ------------------------------------------------ fused prep + edge counting:
//  blocks [0, CNT_BLOCKS)       : per-node counts (global atomics) + bucket histogram
//  blocks [CNT, CNT+256)        : W1/W2 -> f16 hi/lo planes (k-major swizzle)
//  blocks [CNT+256, ...)        : x fp32 -> fp16
// Wg layout: (((kc*2 + plane)*4 + q)*128 + col)*8 + j ; k = kc*32+q*8+j
__global__ void prep_k(const float* __restrict__ x, __half* __restrict__ y, int n4,
                       const float* __restrict__ W1s, const float* __restrict__ W1n,
                       const float* __restrict__ W2s, const float* __restrict__ W2n,
                       unsigned short* __restrict__ Wg1, unsigned short* __restrict__ Wg2,
                       const int* __restrict__ dst, int* __restrict__ counts,
                       int* __restrict__ bucket_counts,
                       int E, int nb, int N, float* __restrict__ xpad) {
    __shared__ int hist[NB_MAX];
    int b = blockIdx.x;
    int t = threadIdx.x;
    if (b < CNT_BLOCKS) {          // counting (scheduled first -> overlaps with x/W prep)
        if (b == 0 && t < 64) xpad[t] = 0.f;   // zero-row pad for aggregate tail
        for (int i = t; i < nb; i += 256) hist[i] = 0;
        __syncthreads();
        for (int i = b * 256 + t; i < E; i += CNT_BLOCKS * 256) {
            int d = dst[i];
            d = min(max(d, 0), N - 1);         // defensive clamp (no-op for valid input)
            atomicAdd(&hist[d >> 8], 1);       // LDS bucket histogram
            atomicAdd(&counts[d], 1);          // fire-and-forget per-node count
        }
        __syncthreads();
        for (int i = t; i < nb; i += 256) {
            int c = hist[i];
            if (c) atomicAdd(&bucket_counts[i], c);
        }
        return;
    }
    int wb = b - CNT_BLOCKS;
    if (wb < 256) {                // weight hi/lo split
        int sel = wb >> 7;         // 0: W1, 1: W2
        int lb  = wb & 127;
        const float* Ws = sel ? W2s : W1s;
        const float* Wn = sel ? W2n : W1n;
        unsigned short* Wg = sel ? Wg2 : Wg1;
        int idx = lb * 256 + t;    // 0 .. 32767
        int col = idx >> 8;
        int k   = idx & 255;
        float v = (k < 128) ? Ws[k * D + col] : Wn[(k - 128) * D + col];
        _Float16 hv = (_Float16)v;
        _Float16 lv = (_Float16)(v - (float)hv);
        int kc = k >> 5, q = (k >> 3) & 3, j = k & 7;
        Wg[(((kc * 2 + 0) * 4 + q) * 128 + col) * 8 + j] = *(unsigned short*)&hv;
        Wg[(((kc * 2 + 1) * 4 + q) * 128 + col) * 8 + j] = *(unsigned short*)&lv;
        return;
    }
    int i = (b - CNT_BLOCKS - 256) * 256 + t;
    if (i < n4) {
        float4 v = *(const float4*)(x + (size_t)i * 4);
        __half2 h0 = __floats2half2_rn(v.x, v.y);
        __half2 h1 = __floats2half2_rn(v.z, v.w);
        __half2* o = (__half2*)(y + (size_t)i * 4);
        o[0] = h0; o[1] = h1;
    }
}

// ------------------------------------------------ per-node offsets + cursors
// One block per 256-node bucket. Bucket base e0 via redundant in-block scan of
// bucket_counts; per-node offsets via block scan of counts. Writes offcnt (for
// the aggregate) and rewrites counts[node] -> cursor (scatter allocation ptr);
// in-place reuse is safe: each thread reads its own count before the write.
__global__ __launch_bounds__(256)
void offsets_k(int* __restrict__ counts_cursor,
               const int* __restrict__ bucket_counts,
               int2* __restrict__ offcnt, int N) {
    __shared__ int sh[256];
    __shared__ int e0s;
    int t = threadIdx.x;
    int b = blockIdx.x;
    // global exclusive scan over bucket_counts (4 buckets/thread covers 1024)
    int t4 = t * 4;
    int g0 = bucket_counts[t4], g1 = bucket_counts[t4 + 1];
    int g2 = bucket_counts[t4 + 2], g3 = bucket_counts[t4 + 3];
    int gs = g0 + g1 + g2 + g3;
    sh[t] = gs;
    __syncthreads();
    for (int off = 1; off < 256; off <<= 1) {
        int v = 0;
        if (t >= off) v = sh[t - off];
        __syncthreads();
        if (t >= off) sh[t] += v;
        __syncthreads();
    }
    if (t == (b >> 2)) {
        int ex = sh[t] - gs;
        int v[4] = {g0, g1, g2, g3};
        #pragma unroll
        for (int j = 0; j < 4; ++j)
            if (j < (b & 3)) ex += v[j];
        e0s = ex;
    }
    __syncthreads();
    int e0 = e0s;
    // per-node exclusive scan within the bucket (read count BEFORE cursor write)
    int node = (b << 8) + t;
    int c = (node < N) ? counts_cursor[node] : 0;
    sh[t] = c;
    __syncthreads();
    for (int off = 1; off < 256; off <<= 1) {
        int v = 0;
        if (t >= off) v = sh[t - off];
        __syncthreads();
        if (t >= off) sh[t] += v;
        __syncthreads();
    }
    int excl = sh[t] - c;
    if (node < N) {
        int o = e0 + excl;
        offcnt[node] = make_int2(o, c);
        counts_cursor[node] = o;      // becomes the scatter cursor
    }
}

// ------------------------------------------------ one-pass CSR scatter
// pos = atomicAdd(cursor[dst]) -> edge_src[pos] = src. Per-node cursors (~16
// edges/counter) -> negligible contention; no LDS, tiny VGPR -> full occupancy;
// massive TLP hides the atomic-return + scattered-store latency. Positions are
// clamped to [0,E) so no state corruption can produce an OOB store.
__global__ __launch_bounds__(256)
void scatter_k(const int* __restrict__ src, const int* __restrict__ dst,
               int* __restrict__ cursor, int* __restrict__ edge_src, int E, int N) {
    int i = (blockIdx.x * 256 + threadIdx.x) * 4;
    if (i + 3 < E) {
        int4 s4 = *(const int4*)(src + i);
        int4 d4 = *(const int4*)(dst + i);
        int c0 = min(max(d4.x, 0), N - 1);
        int c1 = min(max(d4.y, 0), N - 1);
        int c2 = min(max(d4.z, 0), N - 1);
        int c3 = min(max(d4.w, 0), N - 1);
        int p0 = min(atomicAdd(&cursor[c0], 1), E - 1);
        int p1 = min(atomicAdd(&cursor[c1], 1), E - 1);
        int p2 = min(atomicAdd(&cursor[c2], 1), E - 1);
        int p3 = min(atomicAdd(&cursor[c3], 1), E - 1);
        edge_src[p0] = s4.x;
        edge_src[p1] = s4.y;
        edge_src[p2] = s4.z;
        edge_src[p3] = s4.w;
    } else {
        for (; i < E; ++i) {
            int c = min(max(dst[i], 0), N - 1);
            int p = min(atomicAdd(&cursor[c], 1), E - 1);
            edge_src[p] = src[i];
        }
    }
}

// ------------------------------------------------ neighbor mean, fp16 in/out
// one wave per dst node; 16 lanes x 16B per row; 16 edges per inner iter.
// Invalid lanes gather the all-zero pad row (index n) -> no tail mask math;
// accumulation via v_fma_mix_f32 (f16 src, f32 acc) -> 1 VALU op per element.
// NOTE (R1/R2 measured): pinned at ~3.7 TB/s L2-fill rate with FETCH ~= 8 XCD x
// 22MB compulsory traffic -> at its structural roofline (~55 us).
__global__ void aggregate_f16_k(const __half* __restrict__ x,
                                const int* __restrict__ edge_src,
                                const int2* __restrict__ offcnt,
                                __half* __restrict__ agg, int n) {
    int wid  = (blockIdx.x * blockDim.x + threadIdx.x) >> 6;
    int lane = threadIdx.x & 63;
    if (wid >= n) return;
    int sg  = lane >> 4;     // 0..3: edge slot within each group of 4
    int sub = lane & 15;     // 16 lanes cover one 256B row
    int2 oc = offcnt[wid];
    int start = oc.x;
    int cnt   = oc.y;
    float one = 1.0f;
    float acc[8] = {0.f, 0.f, 0.f, 0.f, 0.f, 0.f, 0.f, 0.f};
    for (int base = 0; base < cnt; base += 64) {
        int valid = min(64, cnt - base);
        int s = (lane < valid) ? edge_src[start + base + lane] : n;  // n = zero row
        s = min(max(s, 0), n);        // defensive clamp (pad row worst-case)
        for (int k0 = 0; k0 < valid; k0 += 16) {
            float4 raw[4];
            #pragma unroll
            for (int u = 0; u < 4; ++u) {
                int row = __shfl(s, (k0 + 4 * u + sg) & 63);
                raw[u] = *(const float4*)(x + (size_t)row * D + sub * 8);
            }
            #pragma unroll
            for (int u = 0; u < 4; ++u) {
                const unsigned* dw = (const unsigned*)&raw[u];
                #pragma unroll
                for (int j = 0; j < 4; ++j) {
                    FMA_MIX_LO(acc[2 * j],     dw[j], one);
                    FMA_MIX_HI(acc[2 * j + 1], dw[j], one);
                }
            }
        }
    }
    #pragma unroll
    for (int j = 0; j < 8; ++j) {
        acc[j] += __shfl(acc[j], lane ^ 16);
        acc[j] += __shfl(acc[j], lane ^ 32);
    }
    if (sg == 0) {
        float inv = 1.0f / fmaxf((float)cnt, 1.0f);
        union { __half2 h2[4]; short8 s8; } u;
        #pragma unroll
        for (int j = 0; j < 4; ++j)
            u.h2[j] = __floats2half2_rn(acc[2 * j] * inv, acc[2 * j + 1] * inv);
        *(short8*)(agg + (size_t)wid * D + sub * 8) = u.s8;
    }
}

// ------------------------------------------------ fp16 2-term MFMA GEMM, LDS-staged B
// C = A0 @ W[:128] + A1 @ W[128:] + b  with W = Whi + Wlo (f16 split)
__global__ __launch_bounds__(512)
void mfma_gemm_k(const _Float16* __restrict__ A0, const _Float16* __restrict__ A1,
                 const unsigned short* __restrict__ Wg,
                 const float* __restrict__ bias,
                 float* __restrict__ C, __half* __restrict__ Ch,
                 int n, int out_mode) {
    __shared__ __align__(16) unsigned short lds_b[8192];   // 16 KB
    int t = threadIdx.x;
    int w = t >> 6;
    int l = t & 63;
    int m = l & 15;          // A row within tile / B,C col within tile
    int q = l >> 4;          // quad
    int r0 = blockIdx.x * 256 + w * 32;

    f32x4 acc[2][8];
    #pragma unroll
    for (int rt = 0; rt < 2; ++rt)
        #pragma unroll
        for (int ct = 0; ct < 8; ++ct)
            acc[rt][ct] = (f32x4){0.f, 0.f, 0.f, 0.f};

    for (int kc = 0; kc < 8; ++kc) {
        // async stage B chunk (16 KB contiguous) into LDS: 1024 x 16B, 2/thread
        const unsigned short* gk = Wg + (size_t)kc * 8192;
        #pragma unroll
        for (int i = 0; i < 2; ++i) {
            int e = i * 512 + t;
            __builtin_amdgcn_global_load_lds(AS1(gk + e * 8), AS3(lds_b + e * 8), 16, 0, 0);
        }
        // A fragments (fp16, 16B each) straight from global
        const _Float16* __restrict__ A = (kc < 4) ? A0 : A1;
        int ka = (kc & 3) * 32;
        half8 a[2];
        #pragma unroll
        for (int rt = 0; rt < 2; ++rt) {
            int row = r0 + rt * 16 + m;
            half8 v = (half8){0, 0, 0, 0, 0, 0, 0, 0};
            if (row < n) v = *(const half8*)(A + (size_t)row * D + ka + q * 8);
            a[rt] = v;
        }
        __syncthreads();     // drains global_load_lds + barrier

        #pragma unroll
        for (int ct = 0; ct < 8; ++ct) {
            half8 bh = *(const half8*)&lds_b[(size_t)(q * 128 + ct * 16 + m) * 8];
            half8 bl = *(const half8*)&lds_b[(size_t)((4 + q) * 128 + ct * 16 + m) * 8];
            #pragma unroll
            for (int rt = 0; rt < 2; ++rt) {
                acc[rt][ct] = __builtin_amdgcn_mfma_f32_16x16x32_f16(a[rt], bh, acc[rt][ct], 0, 0, 0);
                acc[rt][ct] = __builtin_amdgcn_mfma_f32_16x16x32_f16(a[rt], bl, acc[rt][ct], 0, 0, 0);
            }
        }
        __syncthreads();     // LDS reads done before next stage overwrites
    }

    #pragma unroll
    for (int ct = 0; ct < 8; ++ct) {
        int col = ct * 16 + m;
        float bb = bias[col];
        #pragma unroll
        for (int rt = 0; rt < 2; ++rt) {
            #pragma unroll
            for (int r = 0; r < 4; ++r) {
                int row = r0 + rt * 16 + q * 4 + r;
                if (row < n) {
                    float v = acc[rt][ct][r] + bb;
                    if (out_mode) {
                        v = fmaxf(v, 0.f);
                        Ch[(size_t)row * D + col] = __float2half(v);
                    } else {
                        C[(size_t)row * D + col] = v;
                    }
                }
            }
        }
    }
}

// ------------------------------------------------------------------- launch
extern "C" void kernel_launch(void* const* d_in, const int* in_sizes, int n_in,
                              void* d_out, int out_size, void* d_ws, size_t ws_size,
                              hipStream_t stream) {
    const float* in_feat = (const float*)d_in[0];
    const float* W1s     = (const float*)d_in[1];
    const float* W1n     = (const float*)d_in[2];
    const float* b1      = (const float*)d_in[3];
    const float* W2s     = (const float*)d_in[4];
    const float* W2n     = (const float*)d_in[5];
    const float* b2      = (const float*)d_in[6];
    const int*   src     = (const int*)d_in[7];
    const int*   dst     = (const int*)d_in[8];

    const int N  = in_sizes[0] / D;
    const int E  = in_sizes[7];
    const int NB = (N + 255) >> 8;     // 256-node buckets

    // workspace layout (same footprint as the R3 kernel that ran clean)
    char* base = (char*)d_ws;
    size_t off = 0;
    __half* agg16 = (__half*)(base + off); off += (size_t)N * D * 2;        // neighbor means
    __half* xh16  = (__half*)(base + off); off += ((size_t)N * D + D) * 2;  // x16 (+1 zero row), then h16 in-place
    int* edge_src = (int*)(base + off);    off += (size_t)E * 4;
    int2* offcnt  = (int2*)(base + off);   off += (size_t)(N + 2) * 8;
    unsigned short* Wg1 = (unsigned short*)(base + off); off += 65536 * 2;
    unsigned short* Wg2 = (unsigned short*)(base + off); off += 65536 * 2;
    int* counts        = (int*)(base + off); off += (size_t)N * 4;          // counts, then cursor (in-place)
    int* bucket_counts = (int*)(base + off); off += NB_MAX * 4;             // contiguous -> one memset

    float* xpad = (float*)(xh16 + (size_t)N * D);   // 256B zero row at index N

    const int n4 = (N * D) / 4;
    const int xb = (n4 + 255) / 256;
    const int sblk = (E / 4 + 255) / 256;           // scatter blocks (4 edges/lane)

    hipMemsetAsync(counts, 0, (size_t)N * 4 + NB_MAX * 4, stream);

    // fused prep: per-node + bucket counting (first, overlaps), W split, x->fp16
    hipLaunchKernelGGL(prep_k, dim3(CNT_BLOCKS + 256 + xb), dim3(256), 0, stream,
                       in_feat, xh16, n4, W1s, W1n, W2s, W2n, Wg1, Wg2,
                       dst, counts, bucket_counts, E, NB, N, xpad);

    // CSR: offsets from counts (cursor in-place), then one-pass direct scatter
    hipLaunchKernelGGL(offsets_k, dim3(NB), dim3(256), 0, stream,
                       counts, bucket_counts, offcnt, N);
    hipLaunchKernelGGL(scatter_k, dim3(sblk), dim3(256), 0, stream,
                       src, dst, counts, edge_src, E, N);

    const dim3 aggGrid(((size_t)N * 64 + 255) / 256);
    const dim3 gemmGrid((N + 255) / 256);

    // layer 1: agg(x16) -> gemm -> h16 (in-place into xh16; fp32 h never materialized)
    hipLaunchKernelGGL(aggregate_f16_k, aggGrid, dim3(256), 0, stream,
                       xh16, edge_src, offcnt, agg16, N);
    hipLaunchKernelGGL(mfma_gemm_k, gemmGrid, dim3(512), 0, stream,
                       (const _Float16*)xh16, (const _Float16*)agg16, Wg1, b1,
                       (float*)nullptr, xh16, N, 1);

    // layer 2: agg(h16) -> gemm -> d_out fp32
    hipLaunchKernelGGL(aggregate_f16_k, aggGrid, dim3(256), 0, stream,
                       xh16, edge_src, offcnt, agg16, N);
    hipLaunchKernelGGL(mfma_gemm_k, gemmGrid, dim3(512), 0, stream,
                       (const _Float16*)xh16, (const _Float16*)agg16, Wg2, b2,
                       (float*)d_out, (__half*)nullptr, N, 0);
}